// Round 12
// baseline (1605.589 us; speedup 1.0000x reference)
//
#include <hip/hip_runtime.h>
#include <hip/hip_bf16.h>

// Round 12: r10 branch2 (128-edge, best known) + gauss/unif register prefetch
// issued before the K-loop (T14) + At double-buffer (1 barrier/iter).
// No launch_bounds cap (r11 lesson: VGPR starvation >> occupancy gain).

#define NN 100000
#define EG 800000
#define EE 262144
#define NB 98

typedef __attribute__((ext_vector_type(8))) short short8;
typedef __attribute__((ext_vector_type(4))) float f32x4;
typedef __attribute__((ext_vector_type(2))) float f32x2;

struct BArgs {
  const int* ea; const int* eb;
  const float* gauss; const float* unif;
  float* o_mean; float* o_ls; float* q_o; float* A_o;
  unsigned* M_o32;
};

__device__ __forceinline__ float lo2f(unsigned u) {
  union { unsigned u; float f; } v; v.u = u << 16; return v.f;
}
__device__ __forceinline__ float hi2f(unsigned u) {
  union { unsigned u; float f; } v; v.u = u & 0xFFFF0000u; return v.f;
}
__device__ __forceinline__ unsigned short f2bf(float f) {
  union { float f; unsigned u; } v; v.f = f;
  return (unsigned short)((v.u + 0x7FFFu + ((v.u >> 16) & 1u)) >> 16);
}
__device__ __forceinline__ unsigned pack2bf(float a, float b) {
  return (unsigned)f2bf(a) | ((unsigned)f2bf(b) << 16);
}
__device__ __forceinline__ int permc(int c) {
  return (c & ~31) | ((c & 15) << 1) | ((c >> 4) & 1);
}

__device__ __forceinline__ float decode_scalar(const void* p) {
  unsigned u = *(const unsigned*)p;
  float f = __uint_as_float(u);
  float af = fabsf(f);
  if (af >= 1e-6f && af <= 1e6f) return f;
  if (u < 1024u) return (float)u;
  return 1.0f;
}

// ---------------- degrees (int4-vectorized) ----------------
__global__ __launch_bounds__(256) void k_deg(const int4* __restrict__ src4,
                                             const int4* __restrict__ dst4,
                                             int* __restrict__ degO,
                                             int* __restrict__ degI) {
  int i = blockIdx.x * 256 + threadIdx.x;
  if (i < EG / 4) {
    int4 s = src4[i];
    int4 d = dst4[i];
    atomicAdd(&degO[s.x], 1); atomicAdd(&degO[s.y], 1);
    atomicAdd(&degO[s.z], 1); atomicAdd(&degO[s.w], 1);
    atomicAdd(&degI[d.x], 1); atomicAdd(&degI[d.y], 1);
    atomicAdd(&degI[d.z], 1); atomicAdd(&degI[d.w], 1);
  }
}

// ---------------- parallel scan ----------------
__global__ __launch_bounds__(1024) void k_scan1(const int* __restrict__ degI,
                                                int* __restrict__ rowptr,
                                                int* __restrict__ bsum) {
  __shared__ int wsum[16];
  int t = threadIdx.x, lane = t & 63, wv = t >> 6;
  int i = blockIdx.x * 1024 + t;
  int v = (i < NN) ? degI[i] : 0;
  int incl = v;
#pragma unroll
  for (int off = 1; off < 64; off <<= 1) {
    int u = __shfl_up(incl, off);
    if (lane >= off) incl += u;
  }
  if (lane == 63) wsum[wv] = incl;
  __syncthreads();
  if (wv == 0 && lane < 16) {
    int s = wsum[lane];
    int si = s;
#pragma unroll
    for (int off = 1; off < 16; off <<= 1) {
      int u = __shfl_up(si, off);
      if (lane >= off) si += u;
    }
    wsum[lane] = si - s;
    if (lane == 15) bsum[blockIdx.x] = si;
  }
  __syncthreads();
  int excl = wsum[wv] + incl - v;
  if (i < NN) rowptr[i] = excl;
}

__global__ __launch_bounds__(128) void k_scan2(int* __restrict__ bsum) {
  __shared__ int w0tot;
  int t = threadIdx.x, lane = t & 63, wv = t >> 6;
  int v = (t < NB) ? bsum[t] : 0;
  int incl = v;
#pragma unroll
  for (int off = 1; off < 64; off <<= 1) {
    int u = __shfl_up(incl, off);
    if (lane >= off) incl += u;
  }
  if (wv == 0 && lane == 63) w0tot = incl;
  __syncthreads();
  int excl = incl - v + (wv ? w0tot : 0);
  if (t < NB) bsum[t] = excl;
}

__global__ __launch_bounds__(1024) void k_scan3(const int* __restrict__ degI,
                                                const int* __restrict__ degO,
                                                int* __restrict__ rowptr,
                                                int* __restrict__ cursor,
                                                const int* __restrict__ bsum,
                                                float* __restrict__ normO,
                                                float* __restrict__ normI) {
  int i = blockIdx.x * 1024 + threadIdx.x;
  if (i < NN) {
    int vv = rowptr[i] + bsum[blockIdx.x];
    rowptr[i] = vv;
    cursor[i] = vv;
    if (i == NN - 1) rowptr[NN] = vv + degI[i];
    int dO = degO[i]; if (dO < 1) dO = 1;
    int dI = degI[i]; if (dI < 1) dI = 1;
    normO[i] = rsqrtf((float)dO);
    normI[i] = rsqrtf((float)dI);
  }
}

// ---------------- fill CSR (int4-vectorized) ----------------
__global__ __launch_bounds__(256) void k_fill(const int4* __restrict__ src4,
                                              const int4* __restrict__ dst4,
                                              int* __restrict__ cursor,
                                              int* __restrict__ csr) {
  int i = blockIdx.x * 256 + threadIdx.x;
  if (i < EG / 4) {
    int4 s = src4[i];
    int4 d = dst4[i];
    csr[atomicAdd(&cursor[d.x], 1)] = s.x;
    csr[atomicAdd(&cursor[d.y], 1)] = s.y;
    csr[atomicAdd(&cursor[d.z], 1)] = s.z;
    csr[atomicAdd(&cursor[d.w], 1)] = s.w;
  }
}

// ---------------- merged weight transposes ----------------
__global__ __launch_bounds__(256) void k_transpose_all(
    const float* __restrict__ W1, const float* __restrict__ W2,
    const float* __restrict__ Wm, const float* __restrict__ Wl,
    const float* __restrict__ Wd1, const float* __restrict__ WdX,
    const float* __restrict__ Wq,
    unsigned short* __restrict__ W1T, unsigned short* __restrict__ W2T,
    unsigned short* __restrict__ WmT, unsigned short* __restrict__ WlT,
    unsigned short* __restrict__ Wd1T, unsigned short* __restrict__ WdXT,
    unsigned short* __restrict__ WqT) {
  int idx = blockIdx.x * 256 + threadIdx.x;
  if (idx < 32768) {
    int n = idx & 255, k = idx >> 8;
    W1T[n * 128 + k] = f2bf(W1[idx]);
  } else if (idx < 98304) {
    int i = idx - 32768;
    int n = i & 255, k = i >> 8;
    W2T[n * 256 + k] = f2bf(W2[i]);
  } else if (idx < 163840) {
    int i = idx - 98304;
    int n = i & 255, k = i >> 8;
    WmT[n * 256 + k] = f2bf(Wm[i]);
  } else if (idx < 229376) {
    int i = idx - 163840;
    int n = i & 255, k = i >> 8;
    WlT[n * 256 + k] = f2bf(Wl[i]);
  } else if (idx < 245760) {
    int i = idx - 229376;
    int n = i & 255, k = i >> 8;
    Wd1T[n * 64 + k] = f2bf(Wd1[i]);
  } else if (idx < 278528) {
    int i = idx - 245760;
    int n = i & 127, k = i >> 7;
    WdXT[n * 256 + k] = f2bf(WdX[i]);
  } else if (idx < 282624) {
    int i = idx - 278528;
    int r = i >> 8, k = i & 255;
    WqT[i] = (r < 4) ? f2bf(Wq[k * 4 + r]) : (unsigned short)0;
  }
}

// ---------------- gather layer 1 (f32 x, 2x unrolled) ----------------
__global__ __launch_bounds__(256) void k_gather1(
    const float* __restrict__ x, const int* __restrict__ rowptr,
    const int* __restrict__ csr, const float* __restrict__ normO,
    const float* __restrict__ normI, unsigned short* __restrict__ agg) {
  int wid = (blockIdx.x * 256 + threadIdx.x) >> 6;
  int lane = threadIdx.x & 63;
  int half = lane >> 5, fl = lane & 31;
  int nw = (gridDim.x * 256) >> 6;
  for (int n = wid; n < NN; n += nw) {
    int beg = rowptr[n], end = rowptr[n + 1];
    float a0 = 0.f, a1 = 0.f, a2 = 0.f, a3 = 0.f;
    float b0 = 0.f, b1 = 0.f, b2 = 0.f, b3 = 0.f;
    int i = beg + half;
    for (; i + 2 < end; i += 4) {
      int s0 = csr[i], s1 = csr[i + 2];
      float ns0 = normO[s0], ns1 = normO[s1];
      float4 v0 = *(const float4*)(x + ((size_t)s0 << 7) + (fl << 2));
      float4 v1 = *(const float4*)(x + ((size_t)s1 << 7) + (fl << 2));
      a0 += ns0 * v0.x; a1 += ns0 * v0.y; a2 += ns0 * v0.z; a3 += ns0 * v0.w;
      b0 += ns1 * v1.x; b1 += ns1 * v1.y; b2 += ns1 * v1.z; b3 += ns1 * v1.w;
    }
    for (; i < end; i += 2) {
      int s0 = csr[i];
      float ns0 = normO[s0];
      float4 v0 = *(const float4*)(x + ((size_t)s0 << 7) + (fl << 2));
      a0 += ns0 * v0.x; a1 += ns0 * v0.y; a2 += ns0 * v0.z; a3 += ns0 * v0.w;
    }
    a0 += b0; a1 += b1; a2 += b2; a3 += b3;
    a0 += __shfl_xor(a0, 32); a1 += __shfl_xor(a1, 32);
    a2 += __shfl_xor(a2, 32); a3 += __shfl_xor(a3, 32);
    if (lane < 32) {
      float ni = normI[n];
      *(uint2*)(agg + ((size_t)n << 7) + (fl << 2)) =
          make_uint2(pack2bf(a0 * ni, a1 * ni), pack2bf(a2 * ni, a3 * ni));
    }
  }
}

// ---------------- gather layer 2 (2x unrolled) ----------------
__global__ __launch_bounds__(256) void k_gather2(
    const unsigned short* __restrict__ h1s, const int* __restrict__ rowptr,
    const int* __restrict__ csr, const float* __restrict__ normI,
    unsigned short* __restrict__ agg) {
  int wid = (blockIdx.x * 256 + threadIdx.x) >> 6;
  int lane = threadIdx.x & 63;
  int half = lane >> 5, fl = lane & 31;
  int nw = (gridDim.x * 256) >> 6;
  for (int n = wid; n < NN; n += nw) {
    int beg = rowptr[n], end = rowptr[n + 1];
    float a0 = 0.f, a1 = 0.f, a2 = 0.f, a3 = 0.f, a4 = 0.f, a5 = 0.f, a6 = 0.f, a7 = 0.f;
    float c0 = 0.f, c1 = 0.f, c2 = 0.f, c3 = 0.f, c4 = 0.f, c5 = 0.f, c6 = 0.f, c7 = 0.f;
    int i = beg + half;
    for (; i + 2 < end; i += 4) {
      int s0 = csr[i], s1 = csr[i + 2];
      uint4 v = *(const uint4*)(h1s + ((size_t)s0 << 8) + (fl << 3));
      uint4 u = *(const uint4*)(h1s + ((size_t)s1 << 8) + (fl << 3));
      a0 += lo2f(v.x); a1 += hi2f(v.x);
      a2 += lo2f(v.y); a3 += hi2f(v.y);
      a4 += lo2f(v.z); a5 += hi2f(v.z);
      a6 += lo2f(v.w); a7 += hi2f(v.w);
      c0 += lo2f(u.x); c1 += hi2f(u.x);
      c2 += lo2f(u.y); c3 += hi2f(u.y);
      c4 += lo2f(u.z); c5 += hi2f(u.z);
      c6 += lo2f(u.w); c7 += hi2f(u.w);
    }
    for (; i < end; i += 2) {
      int s0 = csr[i];
      uint4 v = *(const uint4*)(h1s + ((size_t)s0 << 8) + (fl << 3));
      a0 += lo2f(v.x); a1 += hi2f(v.x);
      a2 += lo2f(v.y); a3 += hi2f(v.y);
      a4 += lo2f(v.z); a5 += hi2f(v.z);
      a6 += lo2f(v.w); a7 += hi2f(v.w);
    }
    a0 += c0; a1 += c1; a2 += c2; a3 += c3;
    a4 += c4; a5 += c5; a6 += c6; a7 += c7;
    a0 += __shfl_xor(a0, 32); a1 += __shfl_xor(a1, 32);
    a2 += __shfl_xor(a2, 32); a3 += __shfl_xor(a3, 32);
    a4 += __shfl_xor(a4, 32); a5 += __shfl_xor(a5, 32);
    a6 += __shfl_xor(a6, 32); a7 += __shfl_xor(a7, 32);
    if (lane < 32) {
      float ni = normI[n];
      uint4 o;
      o.x = pack2bf(a0 * ni, a1 * ni);
      o.y = pack2bf(a2 * ni, a3 * ni);
      o.z = pack2bf(a4 * ni, a5 * ni);
      o.w = pack2bf(a6 * ni, a7 * ni);
      *(uint4*)(agg + ((size_t)n << 8) + (fl << 3)) = o;
    }
  }
}

// ---------------- encoder GEMM ----------------
template <int K, bool RELU, bool OSCALE>
__global__ __launch_bounds__(256) void k_gemm(
    const unsigned short* __restrict__ A, const float* __restrict__ oscale,
    const unsigned short* __restrict__ WT, const float* __restrict__ bias,
    unsigned short* __restrict__ C, int M) {
  __shared__ __align__(16) short At[128 * 40];
  __shared__ __align__(16) short Bt[256 * 40];
  const int t = threadIdx.x;
  const int row0 = blockIdx.x * 128;
  const int lane = t & 63, wave = t >> 6;
  const int wr = (wave >> 1) << 6;
  const int wcc = (wave & 1) << 7;
  const int lrow = lane & 15, lhi = lane >> 4;

  f32x4 acc[4][8];
#pragma unroll
  for (int m = 0; m < 4; ++m)
#pragma unroll
    for (int n = 0; n < 8; ++n) acc[m][n] = (f32x4){0.f, 0.f, 0.f, 0.f};

  for (int k0 = 0; k0 < K; k0 += 32) {
    if (k0) __syncthreads();
#pragma unroll
    for (int it = 0; it < 2; ++it) {
      int idx = t + it * 256;
      int r = idx >> 2, c8 = (idx & 3) << 3;
      int grow = row0 + r;
      int4 tv = {0, 0, 0, 0};
      if (grow < M) tv = *(const int4*)(A + (size_t)grow * K + k0 + c8);
      *(int4*)&At[r * 40 + c8] = tv;
    }
    {
      const unsigned short* wt = WT + (size_t)permc(t) * K + k0;
      *(int4*)&Bt[t * 40 + 0] = *(const int4*)(wt);
      *(int4*)&Bt[t * 40 + 8] = *(const int4*)(wt + 8);
      *(int4*)&Bt[t * 40 + 16] = *(const int4*)(wt + 16);
      *(int4*)&Bt[t * 40 + 24] = *(const int4*)(wt + 24);
    }
    __syncthreads();
    short8 a[4], b[8];
#pragma unroll
    for (int m = 0; m < 4; ++m)
      a[m] = *(const short8*)&At[(wr + m * 16 + lrow) * 40 + lhi * 8];
#pragma unroll
    for (int n = 0; n < 8; ++n)
      b[n] = *(const short8*)&Bt[(wcc + n * 16 + lrow) * 40 + lhi * 8];
#pragma unroll
    for (int m = 0; m < 4; ++m)
#pragma unroll
      for (int n = 0; n < 8; ++n)
        acc[m][n] = __builtin_amdgcn_mfma_f32_16x16x32_bf16(a[m], b[n], acc[m][n], 0, 0, 0);
  }
#pragma unroll
  for (int np = 0; np < 4; ++np) {
    int tc = wcc + np * 32 + (lrow << 1);
    float bv0 = bias[tc], bv1 = bias[tc + 1];
#pragma unroll
    for (int m = 0; m < 4; ++m) {
#pragma unroll
      for (int r = 0; r < 4; ++r) {
        int grow = row0 + wr + m * 16 + lhi * 4 + r;
        if (grow < M) {
          float v0 = acc[m][2 * np][r] + bv0;
          float v1 = acc[m][2 * np + 1][r] + bv1;
          if (RELU) { v0 = fmaxf(v0, 0.f); v1 = fmaxf(v1, 0.f); }
          if (OSCALE) { float s = oscale[grow]; v0 *= s; v1 *= s; }
          *(unsigned*)&C[(size_t)grow * 256 + tc] = pack2bf(v0, v1);
        }
      }
    }
  }
}

// ---------------- fused branch v7: 128 edges, gauss prefetch, At dbuf ----------------
__global__ __launch_bounds__(512) void k_branch2(
    const unsigned short* __restrict__ h, BArgs P0, BArgs P1,
    const void* __restrict__ temp_p,
    const unsigned short* __restrict__ WmT, const float* __restrict__ bm,
    const unsigned short* __restrict__ WlT, const float* __restrict__ bl,
    const unsigned short* __restrict__ WqT, const float* __restrict__ bq,
    const float* __restrict__ Wc, const float* __restrict__ bc) {
  const BArgs P = (blockIdx.x < 2048) ? P0 : P1;
  __shared__ __align__(16) char U[33792];  // At dbuf 2x8KB | Mf f32[128][66]
  short* At = (short*)U;
  float* Mf = (float*)U;
  __shared__ float zS[512];
  __shared__ float qS[512];
  __shared__ float WcT[4 * 68];
  __shared__ float bmS[256], blS[256];
  __shared__ int eaS[128], ebS[128];

  const int t = threadIdx.x;
  const int e0 = (blockIdx.x & 2047) << 7;
  const int lane = t & 63;
  const int wv = t >> 6;
  const int lrow = lane & 15, lhi = lane >> 4;
  const int wc = wv << 5;

  if (t < 256) {
    bmS[t] = bm[t]; blS[t] = bl[t];
    WcT[(t & 3) * 68 + (t >> 2)] = Wc[t];
  } else if (t < 384) {
    eaS[t - 256] = P.ea[e0 + t - 256];
  } else {
    ebS[t - 384] = P.eb[e0 + t - 384];
  }
  __syncthreads();

  f32x4 am[8][2], al[8][2], aq;
#pragma unroll
  for (int m = 0; m < 8; ++m)
#pragma unroll
    for (int n = 0; n < 2; ++n) {
      am[m][n] = (f32x4){0.f, 0.f, 0.f, 0.f};
      al[m][n] = (f32x4){0.f, 0.f, 0.f, 0.f};
    }
  aq = (f32x4){0.f, 0.f, 0.f, 0.f};

  const int ar = t >> 2, as_ = t & 3;
  const int arsw = ((as_ ^ (ar & 3)) << 3);
  const int fsw = (lrow & 3);
  const int tc = wc + (lrow << 1);

  const unsigned short* pa_base = h + ((size_t)eaS[ar] << 8) + (as_ << 3);
  const unsigned short* pb_base = h + ((size_t)ebS[ar] << 8) + (as_ << 3);
  const size_t row0p = (size_t)permc(wc + lrow) << 8;
  const size_t row1p = (size_t)permc(wc + 16 + lrow) << 8;
  const unsigned short* bm0p = WmT + row0p + (lhi << 3);
  const unsigned short* bm1p = WmT + row1p + (lhi << 3);
  const unsigned short* bl0p = WlT + row0p + (lhi << 3);
  const unsigned short* bl1p = WlT + row1p + (lhi << 3);
  const unsigned short* bqp = WqT + ((size_t)lrow << 8) + (lhi << 3);

  // ---- prefetch stream-once inputs into registers (T14): addresses known now ----
  f32x2 gpre[16];
#pragma unroll
  for (int m = 0; m < 8; ++m) {
#pragma unroll
    for (int r = 0; r < 4; r += 2) {  // 16 of 32 rows per thread pair (m x r even/odd split below)
      // handled in full below
    }
  }
  // full 32 values would be 64 regs; prefetch 16 (m 0..7, r in {lhi-dependent rows}) —
  // we prefetch the gauss pair for every (m, r): 8 m x 4 r = 32 loads is too many regs;
  // prefetch half (r=0,1) and issue r=2,3 at K-loop midpoint.
  f32x2 gpre2[16];
#pragma unroll
  for (int m = 0; m < 8; ++m) {
#pragma unroll
    for (int r = 0; r < 2; ++r) {
      int row = m * 16 + lhi * 4 + r;
      gpre[m * 2 + r] = __builtin_nontemporal_load(
          (const f32x2*)(P.gauss + (((size_t)(e0 + row)) << 8) + tc));
    }
  }
  float uupre[4];
#pragma unroll
  for (int r = 0; r < 4; ++r) {
    int el = (wv << 4) + lhi * 4 + r;
    uupre[r] = (lrow < 4) ? P.unif[(((size_t)(e0 + el)) << 2) + lrow] : 0.5f;
  }

  // prologue: fill At[0] with k0=0, prefetch k0=32
  uint4 va = *(const uint4*)pa_base;
  uint4 vb = *(const uint4*)pb_base;
  {
    unsigned w0 = pack2bf(lo2f(va.x) + lo2f(vb.x), hi2f(va.x) + hi2f(vb.x));
    unsigned w1 = pack2bf(lo2f(va.y) + lo2f(vb.y), hi2f(va.y) + hi2f(vb.y));
    unsigned w2 = pack2bf(lo2f(va.z) + lo2f(vb.z), hi2f(va.z) + hi2f(vb.z));
    unsigned w3 = pack2bf(lo2f(va.w) + lo2f(vb.w), hi2f(va.w) + hi2f(vb.w));
    *(int4*)&At[ar * 32 + arsw] = make_int4((int)w0, (int)w1, (int)w2, (int)w3);
  }
  va = *(const uint4*)(pa_base + 32);
  vb = *(const uint4*)(pb_base + 32);
  __syncthreads();

  int cur = 0;
  for (int k0 = 0; k0 < 256; k0 += 32) {
    short8 bmf0 = *(const short8*)(bm0p + k0);
    short8 bmf1 = *(const short8*)(bm1p + k0);
    short8 blf0 = *(const short8*)(bl0p + k0);
    short8 blf1 = *(const short8*)(bl1p + k0);
    short8 bqf = *(const short8*)(bqp + k0);
    if (k0 == 128) {
      // second half of gauss prefetch (r=2,3), issued mid-loop
#pragma unroll
      for (int m = 0; m < 8; ++m)
#pragma unroll
        for (int r = 2; r < 4; ++r) {
          int row = m * 16 + lhi * 4 + r;
          gpre2[m * 2 + r - 2] = __builtin_nontemporal_load(
              (const f32x2*)(P.gauss + (((size_t)(e0 + row)) << 8) + tc));
        }
    }
    const short* ab = &At[cur * 4096];
    short8 a[8], aqa;
#pragma unroll
    for (int m = 0; m < 8; ++m)
      a[m] = *(const short8*)&ab[(m * 16 + lrow) * 32 + ((lhi ^ fsw) << 3)];
    aqa = *(const short8*)&ab[((wv << 4) + lrow) * 32 + ((lhi ^ fsw) << 3)];
    if (k0 < 224) {
      unsigned w0 = pack2bf(lo2f(va.x) + lo2f(vb.x), hi2f(va.x) + hi2f(vb.x));
      unsigned w1 = pack2bf(lo2f(va.y) + lo2f(vb.y), hi2f(va.y) + hi2f(vb.y));
      unsigned w2 = pack2bf(lo2f(va.z) + lo2f(vb.z), hi2f(va.z) + hi2f(vb.z));
      unsigned w3 = pack2bf(lo2f(va.w) + lo2f(vb.w), hi2f(va.w) + hi2f(vb.w));
      *(int4*)&At[(cur ^ 1) * 4096 + ar * 32 + arsw] = make_int4((int)w0, (int)w1, (int)w2, (int)w3);
      if (k0 < 192) {
        va = *(const uint4*)(pa_base + k0 + 64);
        vb = *(const uint4*)(pb_base + k0 + 64);
      }
    }
#pragma unroll
    for (int m = 0; m < 8; ++m) {
      am[m][0] = __builtin_amdgcn_mfma_f32_16x16x32_bf16(a[m], bmf0, am[m][0], 0, 0, 0);
      am[m][1] = __builtin_amdgcn_mfma_f32_16x16x32_bf16(a[m], bmf1, am[m][1], 0, 0, 0);
      al[m][0] = __builtin_amdgcn_mfma_f32_16x16x32_bf16(a[m], blf0, al[m][0], 0, 0, 0);
      al[m][1] = __builtin_amdgcn_mfma_f32_16x16x32_bf16(a[m], blf1, al[m][1], 0, 0, 0);
    }
    aq = __builtin_amdgcn_mfma_f32_16x16x32_bf16(aqa, bqf, aq, 0, 0, 0);
    __syncthreads();
    cur ^= 1;
  }

  // Z phase (uses prefetched unif)
  float invt = 1.0f / decode_scalar(temp_p);
  float qb = (lrow < 4) ? bq[lrow] : 0.f;
#pragma unroll
  for (int r = 0; r < 4; ++r) {
    int el = (wv << 4) + lhi * 4 + r;
    float q = aq[r] + qb;
    float g = -__logf(-__logf(uupre[r] + 1e-7f) + 1e-7f);
    float z = (q + g) * invt;
    float mx = fmaxf(z, __shfl_xor(z, 1));
    mx = fmaxf(mx, __shfl_xor(mx, 2));
    float ez = __expf(z - mx);
    float sz = ez + __shfl_xor(ez, 1);
    sz += __shfl_xor(sz, 2);
    if (lrow < 4) { zS[el * 4 + lrow] = ez / sz; qS[el * 4 + lrow] = q; }
  }
  for (int i = t; i < 128 * 66; i += 512) Mf[i] = 0.f;
  __syncthreads();

  __builtin_nontemporal_store(qS[t], P.q_o + (((size_t)e0) << 2) + t);

  // mean/ls epilogue: gauss already in registers
  const int cidx = wv >> 1;
  const int dd = ((wv & 1) << 5) + (lrow << 1);
  float bm0 = bmS[tc], bm1 = bmS[tc + 1];
  float bl0 = blS[tc], bl1 = blS[tc + 1];
#pragma unroll
  for (int m = 0; m < 8; ++m) {
#pragma unroll
    for (int r = 0; r < 4; ++r) {
      int row = m * 16 + lhi * 4 + r;
      size_t gi = (((size_t)(e0 + row)) << 8) + tc;
      float mv0 = am[m][0][r] + bm0, mv1 = am[m][1][r] + bm1;
      float lv0 = al[m][0][r] + bl0, lv1 = al[m][1][r] + bl1;
      __builtin_nontemporal_store((f32x2){mv0, mv1}, (f32x2*)(P.o_mean + gi));
      __builtin_nontemporal_store((f32x2){lv0, lv1}, (f32x2*)(P.o_ls + gi));
      f32x2 g2 = (r < 2) ? gpre[m * 2 + r] : gpre2[m * 2 + r - 2];
      float zc = zS[(row << 2) + cidx];
      atomicAdd(&Mf[row * 66 + dd], zc * (g2.x * __expf(lv0) + mv0));
      atomicAdd(&Mf[row * 66 + dd + 1], zc * (g2.y * __expf(lv1) + mv1));
    }
  }
  __syncthreads();

  // A phase
  {
    int e = t >> 2, cat = t & 3;
    const float* mrow = &Mf[e * 66];
    const float* wct = &WcT[cat * 68];
    float s = 0.f;
#pragma unroll
    for (int dp = 0; dp < 32; ++dp) {
      float2 m2 = *(const float2*)(mrow + 2 * dp);
      s += m2.x * wct[2 * dp] + m2.y * wct[2 * dp + 1];
    }
    s += bc[cat];
    float smx = fmaxf(s, __shfl_xor(s, 1));
    smx = fmaxf(smx, __shfl_xor(smx, 2));
    float es = __expf(s - smx);
    float ssum = es + __shfl_xor(es, 1);
    ssum += __shfl_xor(ssum, 2);
    __builtin_nontemporal_store(es / ssum, P.A_o + (((size_t)e0) << 2) + t);
  }
  // M write
#pragma unroll
  for (int j = 0; j < 8; ++j) {
    int idx = j * 512 + t;
    int row = idx >> 5, dp = idx & 31;
    float2 m2 = *(const float2*)(&Mf[row * 66 + 2 * dp]);
    P.M_o32[((size_t)(e0 + row)) * 32 + dp] = pack2bf(m2.x, m2.y);
  }
}

// ---------------- fused decoder (r10, unchanged) ----------------
__global__ __launch_bounds__(512) void k_dec2(
    const unsigned short* __restrict__ Mw0, const unsigned short* __restrict__ Mw1,
    const unsigned short* __restrict__ Wd1T, const float* __restrict__ bd1,
    const unsigned short* __restrict__ WdXT, const float* __restrict__ bdX,
    float* __restrict__ Xo0, float* __restrict__ Xo1) {
  const int br = blockIdx.x >> 12;
  const unsigned short* Mw = br ? Mw1 : Mw0;
  float* Xo = br ? Xo1 : Xo0;
  __shared__ __align__(16) char R[65280];
  short* Mt = (short*)R;
  short* Bt1 = (short*)(R + 9216);
  short* X1 = (short*)R;
  short* Bt2 = (short*)(R + 46848);
  const int t = threadIdx.x, lane = t & 63, wv = t >> 6;
  const int lrow = lane & 15, lhi = lane >> 4;
  const int e0 = (blockIdx.x & 4095) << 6;

  const int r2 = t >> 2, base2 = (t & 3) << 4;
  const unsigned short* wpb = WdXT + ((size_t)permc(r2) << 8) + base2;

  {
    int r = t >> 3, c8 = (t & 7) << 3;
    *(int4*)&Mt[r * 72 + c8] = *(const int4*)(Mw + (((size_t)(e0 + r)) << 6) + c8);
  }
  {
    int r1 = t >> 1, base = (t & 1) << 5;
    const unsigned short* wp = Wd1T + ((size_t)permc(r1) << 6) + base;
#pragma unroll
    for (int j = 0; j < 4; ++j)
      *(int4*)&Bt1[r1 * 72 + base + j * 8] = *(const int4*)(wp + j * 8);
  }
  int4 pw0 = *(const int4*)(wpb);
  int4 pw1 = *(const int4*)(wpb + 8);
  __syncthreads();
  f32x4 acc1[4][2];
#pragma unroll
  for (int m = 0; m < 4; ++m)
#pragma unroll
    for (int n = 0; n < 2; ++n) acc1[m][n] = (f32x4){0.f, 0.f, 0.f, 0.f};
  const int wc1 = wv << 5;
  {
    short8 a0[4], a1[4], b0[2], b1[2];
#pragma unroll
    for (int m = 0; m < 4; ++m) {
      a0[m] = *(const short8*)&Mt[(m * 16 + lrow) * 72 + lhi * 8];
      a1[m] = *(const short8*)&Mt[(m * 16 + lrow) * 72 + 32 + lhi * 8];
    }
#pragma unroll
    for (int n = 0; n < 2; ++n) {
      b0[n] = *(const short8*)&Bt1[(wc1 + n * 16 + lrow) * 72 + lhi * 8];
      b1[n] = *(const short8*)&Bt1[(wc1 + n * 16 + lrow) * 72 + 32 + lhi * 8];
    }
#pragma unroll
    for (int m = 0; m < 4; ++m)
#pragma unroll
      for (int n = 0; n < 2; ++n) {
        acc1[m][n] = __builtin_amdgcn_mfma_f32_16x16x32_bf16(a0[m], b0[n], acc1[m][n], 0, 0, 0);
        acc1[m][n] = __builtin_amdgcn_mfma_f32_16x16x32_bf16(a1[m], b1[n], acc1[m][n], 0, 0, 0);
      }
  }
  __syncthreads();
  {
    int tc = wc1 + (lrow << 1);
    float bdv0 = bd1[tc], bdv1 = bd1[tc + 1];
#pragma unroll
    for (int m = 0; m < 4; ++m)
#pragma unroll
      for (int r = 0; r < 4; ++r) {
        int row = m * 16 + lhi * 4 + r;
        float v0 = fmaxf(acc1[m][0][r] + bdv0, 0.f);
        float v1 = fmaxf(acc1[m][1][r] + bdv1, 0.f);
        *(unsigned*)&X1[row * 264 + tc] = pack2bf(v0, v1);
      }
  }

  f32x4 acc2[2][2];
#pragma unroll
  for (int m = 0; m < 2; ++m)
#pragma unroll
    for (int n = 0; n < 2; ++n) acc2[m][n] = (f32x4){0.f, 0.f, 0.f, 0.f};
  const int wr2 = (wv >> 2) << 5, wc2 = (wv & 3) << 5;
  for (int k0 = 0; k0 < 256; k0 += 64) {
    __syncthreads();
    *(int4*)&Bt2[r2 * 72 + base2] = pw0;
    *(int4*)&Bt2[r2 * 72 + base2 + 8] = pw1;
    if (k0 < 192) {
      pw0 = *(const int4*)(wpb + k0 + 64);
      pw1 = *(const int4*)(wpb + k0 + 64 + 8);
    }
    __syncthreads();
    short8 c0[2], c1[2], d0[2], d1[2];
#pragma unroll
    for (int m = 0; m < 2; ++m) {
      c0[m] = *(const short8*)&X1[(wr2 + m * 16 + lrow) * 264 + k0 + lhi * 8];
      c1[m] = *(const short8*)&X1[(wr2 + m * 16 + lrow) * 264 + k0 + 32 + lhi * 8];
    }
#pragma unroll
    for (int n = 0; n < 2; ++n) {
      d0[n] = *(const short8*)&Bt2[(wc2 + n * 16 + lrow) * 72 + lhi * 8];
      d1[n] = *(const short8*)&Bt2[(wc2 + n * 16 + lrow) * 72 + 32 + lhi * 8];
    }
#pragma unroll
    for (int m = 0; m < 2; ++m)
#pragma unroll
      for (int n = 0; n < 2; ++n) {
        acc2[m][n] = __builtin_amdgcn_mfma_f32_16x16x32_bf16(c0[m], d0[n], acc2[m][n], 0, 0, 0);
        acc2[m][n] = __builtin_amdgcn_mfma_f32_16x16x32_bf16(c1[m], d1[n], acc2[m][n], 0, 0, 0);
      }
  }
  {
    int tc2 = wc2 + (lrow << 1);
    float bx0 = bdX[tc2], bx1 = bdX[tc2 + 1];
#pragma unroll
    for (int m = 0; m < 2; ++m)
#pragma unroll
      for (int r = 0; r < 4; ++r) {
        int row = wr2 + m * 16 + lhi * 4 + r;
        float v0 = fmaxf(acc2[m][0][r] + bx0, 0.f);
        float v1 = fmaxf(acc2[m][1][r] + bx1, 0.f);
        __builtin_nontemporal_store((f32x2){v0, v1},
                                    (f32x2*)(Xo + (((size_t)(e0 + row)) << 7) + tc2));
      }
  }
}

extern "C" void kernel_launch(void* const* d_in, const int* in_sizes, int n_in,
                              void* d_out, int out_size, void* d_ws, size_t ws_size,
                              hipStream_t stream) {
  const float* x = (const float*)d_in[0];
  const int* src = (const int*)d_in[1];
  const int* dst = (const int*)d_in[2];
  const int* pos_src = (const int*)d_in[3];
  const int* pos_dst = (const int*)d_in[4];
  const int* neg_src = (const int*)d_in[5];
  const int* neg_dst = (const int*)d_in[6];
  const float* gauss_pos = (const float*)d_in[7];
  const float* gauss_neg = (const float*)d_in[8];
  const float* unif_pos = (const float*)d_in[9];
  const float* unif_neg = (const float*)d_in[10];
  const void* temp_p = d_in[11];
  const float* W1 = (const float*)d_in[12];
  const float* b1 = (const float*)d_in[13];
  const float* W2 = (const float*)d_in[14];
  const float* b2 = (const float*)d_in[15];
  const float* Wm = (const float*)d_in[16];
  const float* bm = (const float*)d_in[17];
  const float* Wl = (const float*)d_in[18];
  const float* bl = (const float*)d_in[19];
  const float* Wq = (const float*)d_in[20];
  const float* bq = (const float*)d_in[21];
  const float* Wd1 = (const float*)d_in[22];
  const float* bd1 = (const float*)d_in[23];
  const float* WdX = (const float*)d_in[24];
  const float* bdX = (const float*)d_in[25];
  const float* Wc = (const float*)d_in[26];
  const float* bc = (const float*)d_in[27];

  char* w = (char*)d_ws;
  int* degO = (int*)w;
  int* degI = (int*)(w + 401408);
  int* rowptr = (int*)(w + 802816);
  int* cursor = (int*)(w + 1204224);
  float* normO = (float*)(w + 1605632);
  float* normI = (float*)(w + 2007040);
  int* csr = (int*)(w + 2408448);
  unsigned short* W1T = (unsigned short*)(w + 5609472);
  unsigned short* W2T = (unsigned short*)(w + 5675008);
  unsigned short* WmT = (unsigned short*)(w + 5806080);
  unsigned short* WlT = (unsigned short*)(w + 5937152);
  unsigned short* Wd1T = (unsigned short*)(w + 6068224);
  unsigned short* WdXT = (unsigned short*)(w + 6100992);
  unsigned short* WqT = (unsigned short*)(w + 6166528);
  int* bsum = (int*)(w + 6174720);
  unsigned short* agg1 = (unsigned short*)(w + 6175232);
  unsigned short* h1s = (unsigned short*)(w + 31775232);
  unsigned short* agg2 = (unsigned short*)(w + 82975232);
  unsigned short* h = (unsigned short*)(w + 134175232);
  unsigned short* Mws0 = (unsigned short*)(w + 185375232);
  unsigned short* Mws1 = (unsigned short*)(w + 218929664);

  float* out = (float*)d_out;
  float* posA = out;
  float* negA = out + 1048576ull;
  float* posX = out + 2097152ull;
  float* negX = out + 35651584ull;
  float* pos_mean = out + 69206016ull;
  float* neg_mean = out + 136314880ull;
  float* pos_logstd = out + 203423744ull;
  float* neg_logstd = out + 270532608ull;
  float* posq = out + 337641472ull;
  float* negq = out + 338690048ull;

  hipMemsetAsync(d_ws, 0, 802816, stream);

  k_deg<<<782, 256, 0, stream>>>((const int4*)src, (const int4*)dst, degO, degI);
  k_scan1<<<NB, 1024, 0, stream>>>(degI, rowptr, bsum);
  k_scan2<<<1, 128, 0, stream>>>(bsum);
  k_scan3<<<NB, 1024, 0, stream>>>(degI, degO, rowptr, cursor, bsum, normO, normI);
  k_fill<<<782, 256, 0, stream>>>((const int4*)src, (const int4*)dst, cursor, csr);
  k_transpose_all<<<1104, 256, 0, stream>>>(W1, W2, Wm, Wl, Wd1, WdX, Wq,
                                            W1T, W2T, WmT, WlT, Wd1T, WdXT, WqT);

  k_gather1<<<2048, 256, 0, stream>>>(x, rowptr, csr, normO, normI, agg1);
  k_gemm<128, true, true><<<782, 256, 0, stream>>>(agg1, normO, W1T, b1, h1s, NN);
  k_gather2<<<2048, 256, 0, stream>>>(h1s, rowptr, csr, normI, agg2);
  k_gemm<256, false, false><<<782, 256, 0, stream>>>(agg2, nullptr, W2T, b2, h, NN);

  BArgs P0 = {pos_src, pos_dst, gauss_pos, unif_pos,
              pos_mean, pos_logstd, posq, posA, (unsigned*)Mws0};
  BArgs P1 = {neg_src, neg_dst, gauss_neg, unif_neg,
              neg_mean, neg_logstd, negq, negA, (unsigned*)Mws1};

  k_branch2<<<4096, 512, 0, stream>>>(h, P0, P1, temp_p,
                                      WmT, bm, WlT, bl, WqT, bq, Wc, bc);
  k_dec2<<<8192, 512, 0, stream>>>(Mws0, Mws1, Wd1T, bd1, WdXT, bdX, posX, negX);
}

// Round 13
// 1368.427 us; speedup vs baseline: 1.1733x; 1.1733x over previous
//
#include <hip/hip_runtime.h>
#include <hip/hip_bf16.h>

// Round 13: exact revert to round-10 configuration (best measured: 1371 us).
// r11 (64-edge + launch_bounds cap) and r12 (gauss register prefetch + dbuf)
// both regressed branch2 via VGPR starvation/spill; r10 is the local optimum.

#define NN 100000
#define EG 800000
#define EE 262144
#define NB 98

typedef __attribute__((ext_vector_type(8))) short short8;
typedef __attribute__((ext_vector_type(4))) float f32x4;
typedef __attribute__((ext_vector_type(2))) float f32x2;

struct BArgs {
  const int* ea; const int* eb;
  const float* gauss; const float* unif;
  float* o_mean; float* o_ls; float* q_o; float* A_o;
  unsigned* M_o32;
};

__device__ __forceinline__ float lo2f(unsigned u) {
  union { unsigned u; float f; } v; v.u = u << 16; return v.f;
}
__device__ __forceinline__ float hi2f(unsigned u) {
  union { unsigned u; float f; } v; v.u = u & 0xFFFF0000u; return v.f;
}
__device__ __forceinline__ unsigned short f2bf(float f) {
  union { float f; unsigned u; } v; v.f = f;
  return (unsigned short)((v.u + 0x7FFFu + ((v.u >> 16) & 1u)) >> 16);
}
__device__ __forceinline__ unsigned pack2bf(float a, float b) {
  return (unsigned)f2bf(a) | ((unsigned)f2bf(b) << 16);
}
__device__ __forceinline__ int permc(int c) {
  return (c & ~31) | ((c & 15) << 1) | ((c >> 4) & 1);
}

__device__ __forceinline__ float decode_scalar(const void* p) {
  unsigned u = *(const unsigned*)p;
  float f = __uint_as_float(u);
  float af = fabsf(f);
  if (af >= 1e-6f && af <= 1e6f) return f;
  if (u < 1024u) return (float)u;
  return 1.0f;
}

// ---------------- degrees (int4-vectorized, 4 edges/thread) ----------------
__global__ __launch_bounds__(256) void k_deg(const int4* __restrict__ src4,
                                             const int4* __restrict__ dst4,
                                             int* __restrict__ degO,
                                             int* __restrict__ degI) {
  int i = blockIdx.x * 256 + threadIdx.x;
  if (i < EG / 4) {
    int4 s = src4[i];
    int4 d = dst4[i];
    atomicAdd(&degO[s.x], 1); atomicAdd(&degO[s.y], 1);
    atomicAdd(&degO[s.z], 1); atomicAdd(&degO[s.w], 1);
    atomicAdd(&degI[d.x], 1); atomicAdd(&degI[d.y], 1);
    atomicAdd(&degI[d.z], 1); atomicAdd(&degI[d.w], 1);
  }
}

// ---------------- parallel scan ----------------
__global__ __launch_bounds__(1024) void k_scan1(const int* __restrict__ degI,
                                                int* __restrict__ rowptr,
                                                int* __restrict__ bsum) {
  __shared__ int wsum[16];
  int t = threadIdx.x, lane = t & 63, wv = t >> 6;
  int i = blockIdx.x * 1024 + t;
  int v = (i < NN) ? degI[i] : 0;
  int incl = v;
#pragma unroll
  for (int off = 1; off < 64; off <<= 1) {
    int u = __shfl_up(incl, off);
    if (lane >= off) incl += u;
  }
  if (lane == 63) wsum[wv] = incl;
  __syncthreads();
  if (wv == 0 && lane < 16) {
    int s = wsum[lane];
    int si = s;
#pragma unroll
    for (int off = 1; off < 16; off <<= 1) {
      int u = __shfl_up(si, off);
      if (lane >= off) si += u;
    }
    wsum[lane] = si - s;
    if (lane == 15) bsum[blockIdx.x] = si;
  }
  __syncthreads();
  int excl = wsum[wv] + incl - v;
  if (i < NN) rowptr[i] = excl;
}

__global__ __launch_bounds__(128) void k_scan2(int* __restrict__ bsum) {
  __shared__ int w0tot;
  int t = threadIdx.x, lane = t & 63, wv = t >> 6;
  int v = (t < NB) ? bsum[t] : 0;
  int incl = v;
#pragma unroll
  for (int off = 1; off < 64; off <<= 1) {
    int u = __shfl_up(incl, off);
    if (lane >= off) incl += u;
  }
  if (wv == 0 && lane == 63) w0tot = incl;
  __syncthreads();
  int excl = incl - v + (wv ? w0tot : 0);
  if (t < NB) bsum[t] = excl;
}

__global__ __launch_bounds__(1024) void k_scan3(const int* __restrict__ degI,
                                                const int* __restrict__ degO,
                                                int* __restrict__ rowptr,
                                                int* __restrict__ cursor,
                                                const int* __restrict__ bsum,
                                                float* __restrict__ normO,
                                                float* __restrict__ normI) {
  int i = blockIdx.x * 1024 + threadIdx.x;
  if (i < NN) {
    int vv = rowptr[i] + bsum[blockIdx.x];
    rowptr[i] = vv;
    cursor[i] = vv;
    if (i == NN - 1) rowptr[NN] = vv + degI[i];
    int dO = degO[i]; if (dO < 1) dO = 1;
    int dI = degI[i]; if (dI < 1) dI = 1;
    normO[i] = rsqrtf((float)dO);
    normI[i] = rsqrtf((float)dI);
  }
}

// ---------------- fill CSR (int4-vectorized) ----------------
__global__ __launch_bounds__(256) void k_fill(const int4* __restrict__ src4,
                                              const int4* __restrict__ dst4,
                                              int* __restrict__ cursor,
                                              int* __restrict__ csr) {
  int i = blockIdx.x * 256 + threadIdx.x;
  if (i < EG / 4) {
    int4 s = src4[i];
    int4 d = dst4[i];
    csr[atomicAdd(&cursor[d.x], 1)] = s.x;
    csr[atomicAdd(&cursor[d.y], 1)] = s.y;
    csr[atomicAdd(&cursor[d.z], 1)] = s.z;
    csr[atomicAdd(&cursor[d.w], 1)] = s.w;
  }
}

// ---------------- merged weight transposes ----------------
__global__ __launch_bounds__(256) void k_transpose_all(
    const float* __restrict__ W1, const float* __restrict__ W2,
    const float* __restrict__ Wm, const float* __restrict__ Wl,
    const float* __restrict__ Wd1, const float* __restrict__ WdX,
    const float* __restrict__ Wq,
    unsigned short* __restrict__ W1T, unsigned short* __restrict__ W2T,
    unsigned short* __restrict__ WmT, unsigned short* __restrict__ WlT,
    unsigned short* __restrict__ Wd1T, unsigned short* __restrict__ WdXT,
    unsigned short* __restrict__ WqT) {
  int idx = blockIdx.x * 256 + threadIdx.x;
  if (idx < 32768) {
    int n = idx & 255, k = idx >> 8;
    W1T[n * 128 + k] = f2bf(W1[idx]);
  } else if (idx < 98304) {
    int i = idx - 32768;
    int n = i & 255, k = i >> 8;
    W2T[n * 256 + k] = f2bf(W2[i]);
  } else if (idx < 163840) {
    int i = idx - 98304;
    int n = i & 255, k = i >> 8;
    WmT[n * 256 + k] = f2bf(Wm[i]);
  } else if (idx < 229376) {
    int i = idx - 163840;
    int n = i & 255, k = i >> 8;
    WlT[n * 256 + k] = f2bf(Wl[i]);
  } else if (idx < 245760) {
    int i = idx - 229376;
    int n = i & 255, k = i >> 8;
    Wd1T[n * 64 + k] = f2bf(Wd1[i]);
  } else if (idx < 278528) {
    int i = idx - 245760;
    int n = i & 127, k = i >> 7;
    WdXT[n * 256 + k] = f2bf(WdX[i]);
  } else if (idx < 282624) {
    int i = idx - 278528;
    int r = i >> 8, k = i & 255;
    WqT[i] = (r < 4) ? f2bf(Wq[k * 4 + r]) : (unsigned short)0;
  }
}

// ---------------- gather layer 1 (f32 x, 2x unrolled) ----------------
__global__ __launch_bounds__(256) void k_gather1(
    const float* __restrict__ x, const int* __restrict__ rowptr,
    const int* __restrict__ csr, const float* __restrict__ normO,
    const float* __restrict__ normI, unsigned short* __restrict__ agg) {
  int wid = (blockIdx.x * 256 + threadIdx.x) >> 6;
  int lane = threadIdx.x & 63;
  int half = lane >> 5, fl = lane & 31;
  int nw = (gridDim.x * 256) >> 6;
  for (int n = wid; n < NN; n += nw) {
    int beg = rowptr[n], end = rowptr[n + 1];
    float a0 = 0.f, a1 = 0.f, a2 = 0.f, a3 = 0.f;
    float b0 = 0.f, b1 = 0.f, b2 = 0.f, b3 = 0.f;
    int i = beg + half;
    for (; i + 2 < end; i += 4) {
      int s0 = csr[i], s1 = csr[i + 2];
      float ns0 = normO[s0], ns1 = normO[s1];
      float4 v0 = *(const float4*)(x + ((size_t)s0 << 7) + (fl << 2));
      float4 v1 = *(const float4*)(x + ((size_t)s1 << 7) + (fl << 2));
      a0 += ns0 * v0.x; a1 += ns0 * v0.y; a2 += ns0 * v0.z; a3 += ns0 * v0.w;
      b0 += ns1 * v1.x; b1 += ns1 * v1.y; b2 += ns1 * v1.z; b3 += ns1 * v1.w;
    }
    for (; i < end; i += 2) {
      int s0 = csr[i];
      float ns0 = normO[s0];
      float4 v0 = *(const float4*)(x + ((size_t)s0 << 7) + (fl << 2));
      a0 += ns0 * v0.x; a1 += ns0 * v0.y; a2 += ns0 * v0.z; a3 += ns0 * v0.w;
    }
    a0 += b0; a1 += b1; a2 += b2; a3 += b3;
    a0 += __shfl_xor(a0, 32); a1 += __shfl_xor(a1, 32);
    a2 += __shfl_xor(a2, 32); a3 += __shfl_xor(a3, 32);
    if (lane < 32) {
      float ni = normI[n];
      *(uint2*)(agg + ((size_t)n << 7) + (fl << 2)) =
          make_uint2(pack2bf(a0 * ni, a1 * ni), pack2bf(a2 * ni, a3 * ni));
    }
  }
}

// ---------------- gather layer 2 (2x unrolled) ----------------
__global__ __launch_bounds__(256) void k_gather2(
    const unsigned short* __restrict__ h1s, const int* __restrict__ rowptr,
    const int* __restrict__ csr, const float* __restrict__ normI,
    unsigned short* __restrict__ agg) {
  int wid = (blockIdx.x * 256 + threadIdx.x) >> 6;
  int lane = threadIdx.x & 63;
  int half = lane >> 5, fl = lane & 31;
  int nw = (gridDim.x * 256) >> 6;
  for (int n = wid; n < NN; n += nw) {
    int beg = rowptr[n], end = rowptr[n + 1];
    float a0 = 0.f, a1 = 0.f, a2 = 0.f, a3 = 0.f, a4 = 0.f, a5 = 0.f, a6 = 0.f, a7 = 0.f;
    float c0 = 0.f, c1 = 0.f, c2 = 0.f, c3 = 0.f, c4 = 0.f, c5 = 0.f, c6 = 0.f, c7 = 0.f;
    int i = beg + half;
    for (; i + 2 < end; i += 4) {
      int s0 = csr[i], s1 = csr[i + 2];
      uint4 v = *(const uint4*)(h1s + ((size_t)s0 << 8) + (fl << 3));
      uint4 u = *(const uint4*)(h1s + ((size_t)s1 << 8) + (fl << 3));
      a0 += lo2f(v.x); a1 += hi2f(v.x);
      a2 += lo2f(v.y); a3 += hi2f(v.y);
      a4 += lo2f(v.z); a5 += hi2f(v.z);
      a6 += lo2f(v.w); a7 += hi2f(v.w);
      c0 += lo2f(u.x); c1 += hi2f(u.x);
      c2 += lo2f(u.y); c3 += hi2f(u.y);
      c4 += lo2f(u.z); c5 += hi2f(u.z);
      c6 += lo2f(u.w); c7 += hi2f(u.w);
    }
    for (; i < end; i += 2) {
      int s0 = csr[i];
      uint4 v = *(const uint4*)(h1s + ((size_t)s0 << 8) + (fl << 3));
      a0 += lo2f(v.x); a1 += hi2f(v.x);
      a2 += lo2f(v.y); a3 += hi2f(v.y);
      a4 += lo2f(v.z); a5 += hi2f(v.z);
      a6 += lo2f(v.w); a7 += hi2f(v.w);
    }
    a0 += c0; a1 += c1; a2 += c2; a3 += c3;
    a4 += c4; a5 += c5; a6 += c6; a7 += c7;
    a0 += __shfl_xor(a0, 32); a1 += __shfl_xor(a1, 32);
    a2 += __shfl_xor(a2, 32); a3 += __shfl_xor(a3, 32);
    a4 += __shfl_xor(a4, 32); a5 += __shfl_xor(a5, 32);
    a6 += __shfl_xor(a6, 32); a7 += __shfl_xor(a7, 32);
    if (lane < 32) {
      float ni = normI[n];
      uint4 o;
      o.x = pack2bf(a0 * ni, a1 * ni);
      o.y = pack2bf(a2 * ni, a3 * ni);
      o.z = pack2bf(a4 * ni, a5 * ni);
      o.w = pack2bf(a6 * ni, a7 * ni);
      *(uint4*)(agg + ((size_t)n << 8) + (fl << 3)) = o;
    }
  }
}

// ---------------- encoder GEMM ----------------
template <int K, bool RELU, bool OSCALE>
__global__ __launch_bounds__(256) void k_gemm(
    const unsigned short* __restrict__ A, const float* __restrict__ oscale,
    const unsigned short* __restrict__ WT, const float* __restrict__ bias,
    unsigned short* __restrict__ C, int M) {
  __shared__ __align__(16) short At[128 * 40];
  __shared__ __align__(16) short Bt[256 * 40];
  const int t = threadIdx.x;
  const int row0 = blockIdx.x * 128;
  const int lane = t & 63, wave = t >> 6;
  const int wr = (wave >> 1) << 6;
  const int wcc = (wave & 1) << 7;
  const int lrow = lane & 15, lhi = lane >> 4;

  f32x4 acc[4][8];
#pragma unroll
  for (int m = 0; m < 4; ++m)
#pragma unroll
    for (int n = 0; n < 8; ++n) acc[m][n] = (f32x4){0.f, 0.f, 0.f, 0.f};

  for (int k0 = 0; k0 < K; k0 += 32) {
    if (k0) __syncthreads();
#pragma unroll
    for (int it = 0; it < 2; ++it) {
      int idx = t + it * 256;
      int r = idx >> 2, c8 = (idx & 3) << 3;
      int grow = row0 + r;
      int4 tv = {0, 0, 0, 0};
      if (grow < M) tv = *(const int4*)(A + (size_t)grow * K + k0 + c8);
      *(int4*)&At[r * 40 + c8] = tv;
    }
    {
      const unsigned short* wt = WT + (size_t)permc(t) * K + k0;
      *(int4*)&Bt[t * 40 + 0] = *(const int4*)(wt);
      *(int4*)&Bt[t * 40 + 8] = *(const int4*)(wt + 8);
      *(int4*)&Bt[t * 40 + 16] = *(const int4*)(wt + 16);
      *(int4*)&Bt[t * 40 + 24] = *(const int4*)(wt + 24);
    }
    __syncthreads();
    short8 a[4], b[8];
#pragma unroll
    for (int m = 0; m < 4; ++m)
      a[m] = *(const short8*)&At[(wr + m * 16 + lrow) * 40 + lhi * 8];
#pragma unroll
    for (int n = 0; n < 8; ++n)
      b[n] = *(const short8*)&Bt[(wcc + n * 16 + lrow) * 40 + lhi * 8];
#pragma unroll
    for (int m = 0; m < 4; ++m)
#pragma unroll
      for (int n = 0; n < 8; ++n)
        acc[m][n] = __builtin_amdgcn_mfma_f32_16x16x32_bf16(a[m], b[n], acc[m][n], 0, 0, 0);
  }
#pragma unroll
  for (int np = 0; np < 4; ++np) {
    int tc = wcc + np * 32 + (lrow << 1);
    float bv0 = bias[tc], bv1 = bias[tc + 1];
#pragma unroll
    for (int m = 0; m < 4; ++m) {
#pragma unroll
      for (int r = 0; r < 4; ++r) {
        int grow = row0 + wr + m * 16 + lhi * 4 + r;
        if (grow < M) {
          float v0 = acc[m][2 * np][r] + bv0;
          float v1 = acc[m][2 * np + 1][r] + bv1;
          if (RELU) { v0 = fmaxf(v0, 0.f); v1 = fmaxf(v1, 0.f); }
          if (OSCALE) { float s = oscale[grow]; v0 *= s; v1 *= s; }
          *(unsigned*)&C[(size_t)grow * 256 + tc] = pack2bf(v0, v1);
        }
      }
    }
  }
}

// ---------------- fused branch (r10 structure, pos+neg merged) ----------------
__global__ __launch_bounds__(512) void k_branch2(
    const unsigned short* __restrict__ h, BArgs P0, BArgs P1,
    const void* __restrict__ temp_p,
    const unsigned short* __restrict__ WmT, const float* __restrict__ bm,
    const unsigned short* __restrict__ WlT, const float* __restrict__ bl,
    const unsigned short* __restrict__ WqT, const float* __restrict__ bq,
    const float* __restrict__ Wc, const float* __restrict__ bc) {
  const BArgs P = (blockIdx.x < 2048) ? P0 : P1;
  __shared__ __align__(16) char U[33792];  // At [128][32] swizzled | Mf f32[128][66]
  short* At = (short*)U;
  float* Mf = (float*)U;
  __shared__ float zS[512];
  __shared__ float qS[512];
  __shared__ float WcT[4 * 68];
  __shared__ float bmS[256], blS[256];
  __shared__ int eaS[128], ebS[128];

  const int t = threadIdx.x;
  const int e0 = (blockIdx.x & 2047) << 7;
  const int lane = t & 63;
  const int wv = t >> 6;
  const int lrow = lane & 15, lhi = lane >> 4;
  const int wc = wv << 5;

  if (t < 256) {
    bmS[t] = bm[t]; blS[t] = bl[t];
    WcT[(t & 3) * 68 + (t >> 2)] = Wc[t];
  } else if (t < 384) {
    eaS[t - 256] = P.ea[e0 + t - 256];
  } else {
    ebS[t - 384] = P.eb[e0 + t - 384];
  }
  __syncthreads();

  f32x4 am[8][2], al[8][2], aq;
#pragma unroll
  for (int m = 0; m < 8; ++m)
#pragma unroll
    for (int n = 0; n < 2; ++n) {
      am[m][n] = (f32x4){0.f, 0.f, 0.f, 0.f};
      al[m][n] = (f32x4){0.f, 0.f, 0.f, 0.f};
    }
  aq = (f32x4){0.f, 0.f, 0.f, 0.f};

  const int ar = t >> 2, as_ = t & 3;
  const int arsw = ((as_ ^ (ar & 3)) << 3);
  const int fsw = (lrow & 3);

  const unsigned short* pa_base = h + ((size_t)eaS[ar] << 8) + (as_ << 3);
  const unsigned short* pb_base = h + ((size_t)ebS[ar] << 8) + (as_ << 3);
  const size_t row0p = (size_t)permc(wc + lrow) << 8;
  const size_t row1p = (size_t)permc(wc + 16 + lrow) << 8;
  const unsigned short* bm0p = WmT + row0p + (lhi << 3);
  const unsigned short* bm1p = WmT + row1p + (lhi << 3);
  const unsigned short* bl0p = WlT + row0p + (lhi << 3);
  const unsigned short* bl1p = WlT + row1p + (lhi << 3);
  const unsigned short* bqp = WqT + ((size_t)lrow << 8) + (lhi << 3);

  uint4 va = *(const uint4*)pa_base;
  uint4 vb = *(const uint4*)pb_base;

  for (int k0 = 0; k0 < 256; k0 += 32) {
    unsigned w0 = pack2bf(lo2f(va.x) + lo2f(vb.x), hi2f(va.x) + hi2f(vb.x));
    unsigned w1 = pack2bf(lo2f(va.y) + lo2f(vb.y), hi2f(va.y) + hi2f(vb.y));
    unsigned w2 = pack2bf(lo2f(va.z) + lo2f(vb.z), hi2f(va.z) + hi2f(vb.z));
    unsigned w3 = pack2bf(lo2f(va.w) + lo2f(vb.w), hi2f(va.w) + hi2f(vb.w));
    if (k0 < 224) {
      va = *(const uint4*)(pa_base + k0 + 32);
      vb = *(const uint4*)(pb_base + k0 + 32);
    }
    short8 bmf0 = *(const short8*)(bm0p + k0);
    short8 bmf1 = *(const short8*)(bm1p + k0);
    short8 blf0 = *(const short8*)(bl0p + k0);
    short8 blf1 = *(const short8*)(bl1p + k0);
    short8 bqf = *(const short8*)(bqp + k0);
    if (k0) __syncthreads();
    *(int4*)&At[ar * 32 + arsw] = make_int4((int)w0, (int)w1, (int)w2, (int)w3);
    __syncthreads();
    short8 a[8], aqa;
#pragma unroll
    for (int m = 0; m < 8; ++m)
      a[m] = *(const short8*)&At[(m * 16 + lrow) * 32 + ((lhi ^ fsw) << 3)];
    aqa = *(const short8*)&At[((wv << 4) + lrow) * 32 + ((lhi ^ fsw) << 3)];
#pragma unroll
    for (int m = 0; m < 8; ++m) {
      am[m][0] = __builtin_amdgcn_mfma_f32_16x16x32_bf16(a[m], bmf0, am[m][0], 0, 0, 0);
      am[m][1] = __builtin_amdgcn_mfma_f32_16x16x32_bf16(a[m], bmf1, am[m][1], 0, 0, 0);
      al[m][0] = __builtin_amdgcn_mfma_f32_16x16x32_bf16(a[m], blf0, al[m][0], 0, 0, 0);
      al[m][1] = __builtin_amdgcn_mfma_f32_16x16x32_bf16(a[m], blf1, al[m][1], 0, 0, 0);
    }
    aq = __builtin_amdgcn_mfma_f32_16x16x32_bf16(aqa, bqf, aq, 0, 0, 0);
  }
  __syncthreads();

  float invt = 1.0f / decode_scalar(temp_p);
  float qb = (lrow < 4) ? bq[lrow] : 0.f;
#pragma unroll
  for (int r = 0; r < 4; ++r) {
    int el = (wv << 4) + lhi * 4 + r;
    float q = aq[r] + qb;
    float uu = 0.5f;
    if (lrow < 4) uu = P.unif[(((size_t)(e0 + el)) << 2) + lrow];
    float g = -__logf(-__logf(uu + 1e-7f) + 1e-7f);
    float z = (q + g) * invt;
    float mx = fmaxf(z, __shfl_xor(z, 1));
    mx = fmaxf(mx, __shfl_xor(mx, 2));
    float ez = __expf(z - mx);
    float sz = ez + __shfl_xor(ez, 1);
    sz += __shfl_xor(sz, 2);
    if (lrow < 4) { zS[el * 4 + lrow] = ez / sz; qS[el * 4 + lrow] = q; }
  }
  for (int i = t; i < 128 * 66; i += 512) Mf[i] = 0.f;
  __syncthreads();

  __builtin_nontemporal_store(qS[t], P.q_o + (((size_t)e0) << 2) + t);

  const int cidx = wv >> 1;
  const int dd = ((wv & 1) << 5) + (lrow << 1);
  const int tc = wc + (lrow << 1);
  float bm0 = bmS[tc], bm1 = bmS[tc + 1];
  float bl0 = blS[tc], bl1 = blS[tc + 1];
#pragma unroll
  for (int m = 0; m < 8; ++m) {
#pragma unroll
    for (int r = 0; r < 4; ++r) {
      int row = m * 16 + lhi * 4 + r;
      size_t gi = (((size_t)(e0 + row)) << 8) + tc;
      float mv0 = am[m][0][r] + bm0, mv1 = am[m][1][r] + bm1;
      float lv0 = al[m][0][r] + bl0, lv1 = al[m][1][r] + bl1;
      __builtin_nontemporal_store((f32x2){mv0, mv1}, (f32x2*)(P.o_mean + gi));
      __builtin_nontemporal_store((f32x2){lv0, lv1}, (f32x2*)(P.o_ls + gi));
      f32x2 g2 = __builtin_nontemporal_load((const f32x2*)(P.gauss + gi));
      float zc = zS[(row << 2) + cidx];
      atomicAdd(&Mf[row * 66 + dd], zc * (g2.x * __expf(lv0) + mv0));
      atomicAdd(&Mf[row * 66 + dd + 1], zc * (g2.y * __expf(lv1) + mv1));
    }
  }
  __syncthreads();

  {
    int e = t >> 2, cat = t & 3;
    const float* mrow = &Mf[e * 66];
    const float* wct = &WcT[cat * 68];
    float s = 0.f;
#pragma unroll
    for (int dp = 0; dp < 32; ++dp) {
      float2 m2 = *(const float2*)(mrow + 2 * dp);
      s += m2.x * wct[2 * dp] + m2.y * wct[2 * dp + 1];
    }
    s += bc[cat];
    float smx = fmaxf(s, __shfl_xor(s, 1));
    smx = fmaxf(smx, __shfl_xor(smx, 2));
    float es = __expf(s - smx);
    float ssum = es + __shfl_xor(es, 1);
    ssum += __shfl_xor(ssum, 2);
    __builtin_nontemporal_store(es / ssum, P.A_o + (((size_t)e0) << 2) + t);
  }
#pragma unroll
  for (int j = 0; j < 8; ++j) {
    int idx = j * 512 + t;
    int row = idx >> 5, dp = idx & 31;
    float2 m2 = *(const float2*)(&Mf[row * 66 + 2 * dp]);
    P.M_o32[((size_t)(e0 + row)) * 32 + dp] = pack2bf(m2.x, m2.y);
  }
}

// ---------------- fused decoder (r10 structure, pos+neg merged) ----------------
__global__ __launch_bounds__(512) void k_dec2(
    const unsigned short* __restrict__ Mw0, const unsigned short* __restrict__ Mw1,
    const unsigned short* __restrict__ Wd1T, const float* __restrict__ bd1,
    const unsigned short* __restrict__ WdXT, const float* __restrict__ bdX,
    float* __restrict__ Xo0, float* __restrict__ Xo1) {
  const int br = blockIdx.x >> 12;
  const unsigned short* Mw = br ? Mw1 : Mw0;
  float* Xo = br ? Xo1 : Xo0;
  __shared__ __align__(16) char R[65280];
  short* Mt = (short*)R;
  short* Bt1 = (short*)(R + 9216);
  short* X1 = (short*)R;
  short* Bt2 = (short*)(R + 46848);
  const int t = threadIdx.x, lane = t & 63, wv = t >> 6;
  const int lrow = lane & 15, lhi = lane >> 4;
  const int e0 = (blockIdx.x & 4095) << 6;

  const int r2 = t >> 2, base2 = (t & 3) << 4;
  const unsigned short* wpb = WdXT + ((size_t)permc(r2) << 8) + base2;

  {
    int r = t >> 3, c8 = (t & 7) << 3;
    *(int4*)&Mt[r * 72 + c8] = *(const int4*)(Mw + (((size_t)(e0 + r)) << 6) + c8);
  }
  {
    int r1 = t >> 1, base = (t & 1) << 5;
    const unsigned short* wp = Wd1T + ((size_t)permc(r1) << 6) + base;
#pragma unroll
    for (int j = 0; j < 4; ++j)
      *(int4*)&Bt1[r1 * 72 + base + j * 8] = *(const int4*)(wp + j * 8);
  }
  int4 pw0 = *(const int4*)(wpb);
  int4 pw1 = *(const int4*)(wpb + 8);
  __syncthreads();
  f32x4 acc1[4][2];
#pragma unroll
  for (int m = 0; m < 4; ++m)
#pragma unroll
    for (int n = 0; n < 2; ++n) acc1[m][n] = (f32x4){0.f, 0.f, 0.f, 0.f};
  const int wc1 = wv << 5;
  {
    short8 a0[4], a1[4], b0[2], b1[2];
#pragma unroll
    for (int m = 0; m < 4; ++m) {
      a0[m] = *(const short8*)&Mt[(m * 16 + lrow) * 72 + lhi * 8];
      a1[m] = *(const short8*)&Mt[(m * 16 + lrow) * 72 + 32 + lhi * 8];
    }
#pragma unroll
    for (int n = 0; n < 2; ++n) {
      b0[n] = *(const short8*)&Bt1[(wc1 + n * 16 + lrow) * 72 + lhi * 8];
      b1[n] = *(const short8*)&Bt1[(wc1 + n * 16 + lrow) * 72 + 32 + lhi * 8];
    }
#pragma unroll
    for (int m = 0; m < 4; ++m)
#pragma unroll
      for (int n = 0; n < 2; ++n) {
        acc1[m][n] = __builtin_amdgcn_mfma_f32_16x16x32_bf16(a0[m], b0[n], acc1[m][n], 0, 0, 0);
        acc1[m][n] = __builtin_amdgcn_mfma_f32_16x16x32_bf16(a1[m], b1[n], acc1[m][n], 0, 0, 0);
      }
  }
  __syncthreads();
  {
    int tc = wc1 + (lrow << 1);
    float bdv0 = bd1[tc], bdv1 = bd1[tc + 1];
#pragma unroll
    for (int m = 0; m < 4; ++m)
#pragma unroll
      for (int r = 0; r < 4; ++r) {
        int row = m * 16 + lhi * 4 + r;
        float v0 = fmaxf(acc1[m][0][r] + bdv0, 0.f);
        float v1 = fmaxf(acc1[m][1][r] + bdv1, 0.f);
        *(unsigned*)&X1[row * 264 + tc] = pack2bf(v0, v1);
      }
  }

  f32x4 acc2[2][2];
#pragma unroll
  for (int m = 0; m < 2; ++m)
#pragma unroll
    for (int n = 0; n < 2; ++n) acc2[m][n] = (f32x4){0.f, 0.f, 0.f, 0.f};
  const int wr2 = (wv >> 2) << 5, wc2 = (wv & 3) << 5;
  for (int k0 = 0; k0 < 256; k0 += 64) {
    __syncthreads();
    *(int4*)&Bt2[r2 * 72 + base2] = pw0;
    *(int4*)&Bt2[r2 * 72 + base2 + 8] = pw1;
    if (k0 < 192) {
      pw0 = *(const int4*)(wpb + k0 + 64);
      pw1 = *(const int4*)(wpb + k0 + 64 + 8);
    }
    __syncthreads();
    short8 c0[2], c1[2], d0[2], d1[2];
#pragma unroll
    for (int m = 0; m < 2; ++m) {
      c0[m] = *(const short8*)&X1[(wr2 + m * 16 + lrow) * 264 + k0 + lhi * 8];
      c1[m] = *(const short8*)&X1[(wr2 + m * 16 + lrow) * 264 + k0 + 32 + lhi * 8];
    }
#pragma unroll
    for (int n = 0; n < 2; ++n) {
      d0[n] = *(const short8*)&Bt2[(wc2 + n * 16 + lrow) * 72 + lhi * 8];
      d1[n] = *(const short8*)&Bt2[(wc2 + n * 16 + lrow) * 72 + 32 + lhi * 8];
    }
#pragma unroll
    for (int m = 0; m < 2; ++m)
#pragma unroll
      for (int n = 0; n < 2; ++n) {
        acc2[m][n] = __builtin_amdgcn_mfma_f32_16x16x32_bf16(c0[m], d0[n], acc2[m][n], 0, 0, 0);
        acc2[m][n] = __builtin_amdgcn_mfma_f32_16x16x32_bf16(c1[m], d1[n], acc2[m][n], 0, 0, 0);
      }
  }
  {
    int tc2 = wc2 + (lrow << 1);
    float bx0 = bdX[tc2], bx1 = bdX[tc2 + 1];
#pragma unroll
    for (int m = 0; m < 2; ++m)
#pragma unroll
      for (int r = 0; r < 4; ++r) {
        int row = wr2 + m * 16 + lhi * 4 + r;
        float v0 = fmaxf(acc2[m][0][r] + bx0, 0.f);
        float v1 = fmaxf(acc2[m][1][r] + bx1, 0.f);
        __builtin_nontemporal_store((f32x2){v0, v1},
                                    (f32x2*)(Xo + (((size_t)(e0 + row)) << 7) + tc2));
      }
  }
}

extern "C" void kernel_launch(void* const* d_in, const int* in_sizes, int n_in,
                              void* d_out, int out_size, void* d_ws, size_t ws_size,
                              hipStream_t stream) {
  const float* x = (const float*)d_in[0];
  const int* src = (const int*)d_in[1];
  const int* dst = (const int*)d_in[2];
  const int* pos_src = (const int*)d_in[3];
  const int* pos_dst = (const int*)d_in[4];
  const int* neg_src = (const int*)d_in[5];
  const int* neg_dst = (const int*)d_in[6];
  const float* gauss_pos = (const float*)d_in[7];
  const float* gauss_neg = (const float*)d_in[8];
  const float* unif_pos = (const float*)d_in[9];
  const float* unif_neg = (const float*)d_in[10];
  const void* temp_p = d_in[11];
  const float* W1 = (const float*)d_in[12];
  const float* b1 = (const float*)d_in[13];
  const float* W2 = (const float*)d_in[14];
  const float* b2 = (const float*)d_in[15];
  const float* Wm = (const float*)d_in[16];
  const float* bm = (const float*)d_in[17];
  const float* Wl = (const float*)d_in[18];
  const float* bl = (const float*)d_in[19];
  const float* Wq = (const float*)d_in[20];
  const float* bq = (const float*)d_in[21];
  const float* Wd1 = (const float*)d_in[22];
  const float* bd1 = (const float*)d_in[23];
  const float* WdX = (const float*)d_in[24];
  const float* bdX = (const float*)d_in[25];
  const float* Wc = (const float*)d_in[26];
  const float* bc = (const float*)d_in[27];

  char* w = (char*)d_ws;
  int* degO = (int*)w;
  int* degI = (int*)(w + 401408);
  int* rowptr = (int*)(w + 802816);
  int* cursor = (int*)(w + 1204224);
  float* normO = (float*)(w + 1605632);
  float* normI = (float*)(w + 2007040);
  int* csr = (int*)(w + 2408448);
  unsigned short* W1T = (unsigned short*)(w + 5609472);
  unsigned short* W2T = (unsigned short*)(w + 5675008);
  unsigned short* WmT = (unsigned short*)(w + 5806080);
  unsigned short* WlT = (unsigned short*)(w + 5937152);
  unsigned short* Wd1T = (unsigned short*)(w + 6068224);
  unsigned short* WdXT = (unsigned short*)(w + 6100992);
  unsigned short* WqT = (unsigned short*)(w + 6166528);
  int* bsum = (int*)(w + 6174720);
  unsigned short* agg1 = (unsigned short*)(w + 6175232);
  unsigned short* h1s = (unsigned short*)(w + 31775232);
  unsigned short* agg2 = (unsigned short*)(w + 82975232);
  unsigned short* h = (unsigned short*)(w + 134175232);
  unsigned short* Mws0 = (unsigned short*)(w + 185375232);
  unsigned short* Mws1 = (unsigned short*)(w + 218929664);

  float* out = (float*)d_out;
  float* posA = out;
  float* negA = out + 1048576ull;
  float* posX = out + 2097152ull;
  float* negX = out + 35651584ull;
  float* pos_mean = out + 69206016ull;
  float* neg_mean = out + 136314880ull;
  float* pos_logstd = out + 203423744ull;
  float* neg_logstd = out + 270532608ull;
  float* posq = out + 337641472ull;
  float* negq = out + 338690048ull;

  hipMemsetAsync(d_ws, 0, 802816, stream);

  k_deg<<<782, 256, 0, stream>>>((const int4*)src, (const int4*)dst, degO, degI);
  k_scan1<<<NB, 1024, 0, stream>>>(degI, rowptr, bsum);
  k_scan2<<<1, 128, 0, stream>>>(bsum);
  k_scan3<<<NB, 1024, 0, stream>>>(degI, degO, rowptr, cursor, bsum, normO, normI);
  k_fill<<<782, 256, 0, stream>>>((const int4*)src, (const int4*)dst, cursor, csr);
  k_transpose_all<<<1104, 256, 0, stream>>>(W1, W2, Wm, Wl, Wd1, WdX, Wq,
                                            W1T, W2T, WmT, WlT, Wd1T, WdXT, WqT);

  k_gather1<<<2048, 256, 0, stream>>>(x, rowptr, csr, normO, normI, agg1);
  k_gemm<128, true, true><<<782, 256, 0, stream>>>(agg1, normO, W1T, b1, h1s, NN);
  k_gather2<<<2048, 256, 0, stream>>>(h1s, rowptr, csr, normI, agg2);
  k_gemm<256, false, false><<<782, 256, 0, stream>>>(agg2, nullptr, W2T, b2, h, NN);

  BArgs P0 = {pos_src, pos_dst, gauss_pos, unif_pos,
              pos_mean, pos_logstd, posq, posA, (unsigned*)Mws0};
  BArgs P1 = {neg_src, neg_dst, gauss_neg, unif_neg,
              neg_mean, neg_logstd, negq, negA, (unsigned*)Mws1};

  k_branch2<<<4096, 512, 0, stream>>>(h, P0, P1, temp_p,
                                      WmT, bm, WlT, bl, WqT, bq, Wc, bc);
  k_dec2<<<8192, 512, 0, stream>>>(Mws0, Mws1, Wd1T, bd1, WdXT, bdX, posX, negX);
}